// Round 6
// baseline (3817.002 us; speedup 1.0000x reference)
//
#include <hip/hip_runtime.h>
#include <cstdint>

// MyRNN: out[b,t,:] = h_t where h_t = tanh(x[b,t,:]@W_xh + b_h + h_{t-1}@W_hh)
// B=64, S=512, D_IN=D_H=1024, fp32 I/O; internal bf16 MFMA.
//
// Round 6 (remove chain links):
//  - NO LDS, NO __syncthreads in the RNN loop: each lane loads its MFMA
//    A-fragments (16B x 32) straight from the coherent point (sc0 sc1),
//    overlapped with MFMA via counted s_waitcnt vmcnt(16)/vmcnt(0).
//  - Arrivals are plain per-wave flag stores flags[bg][ng][w]=t+1 (distinct
//    4B addresses -> no RMW serialization); poll = one dwordx4 per lane over
//    the bg's 256B flag block + __all reduce.

#define DIN 1024
#define DH  1024
#define NB  64
#define NS  512

typedef __attribute__((ext_vector_type(8))) unsigned short us8;
typedef __attribute__((ext_vector_type(8))) __bf16 bf8;
typedef __attribute__((ext_vector_type(4))) float f32x4;
typedef __attribute__((ext_vector_type(4))) unsigned int u32x4;

__device__ __forceinline__ unsigned short f32_bf16(float f) {
  unsigned u = __float_as_uint(f);
  u = (u + 0x7fffu + ((u >> 16) & 1u)) >> 16;
  return (unsigned short)u;
}
__device__ __forceinline__ float bf16_f32(unsigned short h) {
  return __uint_as_float(((unsigned)h) << 16);
}
__device__ __forceinline__ bf8 as_bf8(us8 v) { return __builtin_bit_cast(bf8, v); }

// ---------------------------------------------------------------- transpose
__global__ __launch_bounds__(256) void k_transpose_bf16(
    const float* __restrict__ W, unsigned short* __restrict__ WT) {
  __shared__ float tile[32][33];
  const int b  = blockIdx.x;
  const int bn = (b & 31) * 32;
  const int bk = (b >> 5) * 32;
  const int tx = threadIdx.x & 31, ty = threadIdx.x >> 5;
#pragma unroll
  for (int i = 0; i < 4; ++i)
    tile[ty + i * 8][tx] = W[(size_t)(bk + ty + i * 8) * DH + bn + tx];
  __syncthreads();
#pragma unroll
  for (int i = 0; i < 4; ++i)
    WT[(size_t)(bn + ty + i * 8) * DIN + bk + tx] = f32_bf16(tile[tx][ty + i * 8]);
}

// ---------------------------------------------------------------- phase 1
__device__ __forceinline__ int lds_idx(int row, int slot) {  // ushort units
  return row * 32 + ((slot ^ ((row >> 1) & 3)) << 3);
}

__global__ __launch_bounds__(256) void k_xproj(
    const float* __restrict__ X,             // [B*S][DIN] fp32
    const unsigned short* __restrict__ WT,   // W_xh^T bf16 [n][k]
    unsigned short* __restrict__ XP) {       // bf16 [s][b][h]
  __shared__ unsigned short As[128 * 32];
  __shared__ unsigned short Bs[128 * 32];
  const int tid = threadIdx.x;
  const int m0 = (int)(blockIdx.x >> 3) * 128;
  const int n0 = (int)(blockIdx.x & 7) * 128;
  const int w = tid >> 6, lane = tid & 63;
  const int wm = (w >> 1) * 64, wn = (w & 1) * 64;
  const int l15 = lane & 15, lhi = lane >> 4;
  const int srow = tid >> 1;
  const int s0 = (tid & 1) * 2;
  f32x4 acc[4][4] = {};

  for (int k0 = 0; k0 < DIN; k0 += 32) {
    const float4* ga = reinterpret_cast<const float4*>(
        X + (size_t)(m0 + srow) * DIN + k0 + s0 * 8);
    float4 f0 = ga[0], f1 = ga[1], f2 = ga[2], f3 = ga[3];
    us8 v0, v1;
    v0[0] = f32_bf16(f0.x); v0[1] = f32_bf16(f0.y); v0[2] = f32_bf16(f0.z); v0[3] = f32_bf16(f0.w);
    v0[4] = f32_bf16(f1.x); v0[5] = f32_bf16(f1.y); v0[6] = f32_bf16(f1.z); v0[7] = f32_bf16(f1.w);
    v1[0] = f32_bf16(f2.x); v1[1] = f32_bf16(f2.y); v1[2] = f32_bf16(f2.z); v1[3] = f32_bf16(f2.w);
    v1[4] = f32_bf16(f3.x); v1[5] = f32_bf16(f3.y); v1[6] = f32_bf16(f3.z); v1[7] = f32_bf16(f3.w);
    *(us8*)&As[lds_idx(srow, s0)]     = v0;
    *(us8*)&As[lds_idx(srow, s0 + 1)] = v1;
    const unsigned short* gb = WT + (size_t)(n0 + srow) * DIN + k0 + s0 * 8;
    *(us8*)&Bs[lds_idx(srow, s0)]     = *reinterpret_cast<const us8*>(gb);
    *(us8*)&Bs[lds_idx(srow, s0 + 1)] = *reinterpret_cast<const us8*>(gb + 8);
    __syncthreads();

    bf8 af[4], bfr[4];
#pragma unroll
    for (int i = 0; i < 4; ++i)
      af[i] = as_bf8(*(const us8*)&As[lds_idx(wm + i * 16 + l15, lhi)]);
#pragma unroll
    for (int r = 0; r < 4; ++r)
      bfr[r] = as_bf8(*(const us8*)&Bs[lds_idx(wn + r * 16 + l15, lhi)]);
#pragma unroll
    for (int i = 0; i < 4; ++i)
#pragma unroll
      for (int r = 0; r < 4; ++r)
        acc[i][r] = __builtin_amdgcn_mfma_f32_16x16x32_bf16(af[i], bfr[r], acc[i][r], 0, 0, 0);
    __syncthreads();
  }
#pragma unroll
  for (int i = 0; i < 4; ++i)
#pragma unroll
    for (int r = 0; r < 4; ++r)
#pragma unroll
      for (int j = 0; j < 4; ++j) {
        int gm = m0 + wm + i * 16 + lhi * 4 + j;
        int gn = n0 + wn + r * 16 + l15;
        int orow = ((gm & 511) << 6) | (gm >> 9);
        XP[(size_t)orow * DH + gn] = f32_bf16(acc[i][r][j]);
      }
}

// ---------------------------------------------------------------- phase 2
// 64 WGs x 256 thr. WG g: bg=g>>4 (rows bg*16..+16), ng=g&15; wave w owns
// cols ng*64+w*16..+16. W_hh^T slice resident in 128 VGPRs/wave.
// No LDS, no barriers: per step each lane loads its own A-fragments (32 x
// 16B, sc0sc1) with counted vmcnt overlap into 32 MFMAs.
#define LDH(dst, offs)                                                        \
  asm volatile("global_load_dwordx4 %0, %1, off offset:" offs " sc0 sc1"      \
               : "=v"(dst) : "v"(ha) : "memory")

__global__ __launch_bounds__(256) void k_rnn(
    const unsigned short* __restrict__ WT,  // W_hh^T bf16 [n][k]
    const unsigned short* __restrict__ XP,  // bf16 [s][b][h]
    const float* __restrict__ BH,           // b_h fp32
    float* __restrict__ OUT,                // fp32 [b][s][h]
    unsigned short* __restrict__ H,         // 2 x [NB][DH] bf16
    unsigned int* __restrict__ flags) {     // [4 bg][16 ng][4 w] u32
  const int tid = threadIdx.x, g = blockIdx.x;
  const int w = tid >> 6, lane = tid & 63;
  const int bg = g >> 4, ng = g & 15;
  const int nbase = ng * 64 + w * 16;
  const int rowbase = bg * 16;
  const int l15 = lane & 15, lhi = lane >> 4;
  const int crow = lhi * 4;

  // preload W_hh^T fragments: 32 x 16B per lane = 128 VGPRs
  bf8 bw[32];
  const unsigned short* wp = WT + (size_t)(nbase + l15) * DIN + lhi * 8;
#pragma unroll
  for (int kk = 0; kk < 32; ++kk)
    bw[kk] = as_bf8(*reinterpret_cast<const us8*>(wp + kk * 32));

  const float bh = BH[nbase + l15];
  unsigned int* myflag = flags + bg * 64 + ng * 4 + w;
  // poll source: lane reads 16B chunk (lane&15) of the bg's 256B flag block
  const u32x4* fline = reinterpret_cast<const u32x4*>(flags + bg * 64) + l15;
  // A-fragment base: row rowbase+l15, k-offset lhi*8 (buffer pb adds NB*DH)
  const unsigned short* hA0 = H + (size_t)(rowbase + l15) * DH + lhi * 8;

  // prefetch xp for t=0
  float xq[4];
#pragma unroll
  for (int j = 0; j < 4; ++j)
    xq[j] = bf16_f32(XP[(size_t)(rowbase + crow + j) * DH + nbase + l15]);

  float v[4] = {0.f, 0.f, 0.f, 0.f};

#pragma unroll 1
  for (int t = 0; t < NS; ++t) {
    const int pb = t & 1;
    f32x4 a0 = {}, a1 = {}, a2 = {}, a3 = {};
    if (t > 0) {
      const us8* ha = reinterpret_cast<const us8*>(hA0 + (size_t)pb * (NB * DH));
      us8 hv[32];
      LDH(hv[0], "0");     LDH(hv[1], "64");    LDH(hv[2], "128");   LDH(hv[3], "192");
      LDH(hv[4], "256");   LDH(hv[5], "320");   LDH(hv[6], "384");   LDH(hv[7], "448");
      LDH(hv[8], "512");   LDH(hv[9], "576");   LDH(hv[10], "640");  LDH(hv[11], "704");
      LDH(hv[12], "768");  LDH(hv[13], "832");  LDH(hv[14], "896");  LDH(hv[15], "960");
      LDH(hv[16], "1024"); LDH(hv[17], "1088"); LDH(hv[18], "1152"); LDH(hv[19], "1216");
      LDH(hv[20], "1280"); LDH(hv[21], "1344"); LDH(hv[22], "1408"); LDH(hv[23], "1472");
      LDH(hv[24], "1536"); LDH(hv[25], "1600"); LDH(hv[26], "1664"); LDH(hv[27], "1728");
      LDH(hv[28], "1792"); LDH(hv[29], "1856"); LDH(hv[30], "1920"); LDH(hv[31], "1984");
      asm volatile("s_waitcnt vmcnt(16)" ::: "memory");
      __builtin_amdgcn_sched_barrier(0);  // MFMA must not hoist above the wait
#pragma unroll
      for (int kk = 0; kk < 16; kk += 4) {
        a0 = __builtin_amdgcn_mfma_f32_16x16x32_bf16(as_bf8(hv[kk]),     bw[kk],     a0, 0, 0, 0);
        a1 = __builtin_amdgcn_mfma_f32_16x16x32_bf16(as_bf8(hv[kk + 1]), bw[kk + 1], a1, 0, 0, 0);
        a2 = __builtin_amdgcn_mfma_f32_16x16x32_bf16(as_bf8(hv[kk + 2]), bw[kk + 2], a2, 0, 0, 0);
        a3 = __builtin_amdgcn_mfma_f32_16x16x32_bf16(as_bf8(hv[kk + 3]), bw[kk + 3], a3, 0, 0, 0);
      }
      asm volatile("s_waitcnt vmcnt(0)" ::: "memory");
      __builtin_amdgcn_sched_barrier(0);
#pragma unroll
      for (int kk = 16; kk < 32; kk += 4) {
        a0 = __builtin_amdgcn_mfma_f32_16x16x32_bf16(as_bf8(hv[kk]),     bw[kk],     a0, 0, 0, 0);
        a1 = __builtin_amdgcn_mfma_f32_16x16x32_bf16(as_bf8(hv[kk + 1]), bw[kk + 1], a1, 0, 0, 0);
        a2 = __builtin_amdgcn_mfma_f32_16x16x32_bf16(as_bf8(hv[kk + 2]), bw[kk + 2], a2, 0, 0, 0);
        a3 = __builtin_amdgcn_mfma_f32_16x16x32_bf16(as_bf8(hv[kk + 3]), bw[kk + 3], a3, 0, 0, 0);
      }
    }
    f32x4 s = (a0 + a1) + (a2 + a3);

#pragma unroll
    for (int j = 0; j < 4; ++j) {
      float x = xq[j] + s[j] + bh;
      float e = __expf(-2.f * fabsf(x));
      float r = __fdividef(1.f - e, 1.f + e);
      v[j] = copysignf(r, x);
    }

    if (t < NS - 1) {
      // h stores to coherent point, drain, then plain flag store (no RMW)
      unsigned short* hnext = H + (size_t)(pb ^ 1) * (NB * DH);
#pragma unroll
      for (int j = 0; j < 4; ++j)
        __hip_atomic_store(hnext + (size_t)(rowbase + crow + j) * DH + nbase + l15,
                           f32_bf16(v[j]), __ATOMIC_RELAXED, __HIP_MEMORY_SCOPE_AGENT);
      asm volatile("s_waitcnt vmcnt(0)" ::: "memory");  // drain THIS wave's h
      if (lane == 0)
        __hip_atomic_store(myflag, (unsigned)(t + 1), __ATOMIC_RELAXED,
                           __HIP_MEMORY_SCOPE_AGENT);
      // off-critical-path work rides under the poll
#pragma unroll
      for (int j = 0; j < 4; ++j)
        __builtin_nontemporal_store(
            v[j], &OUT[((size_t)(rowbase + crow + j) * NS + t) * DH + nbase + l15]);
#pragma unroll
      for (int j = 0; j < 4; ++j)
        xq[j] = bf16_f32(XP[(size_t)(((t + 1) << 6) + rowbase + crow + j) * DH +
                            nbase + l15]);
      const unsigned tgt = (unsigned)(t + 1);
      for (;;) {
        u32x4 fv;
        asm volatile("global_load_dwordx4 %0, %1, off sc0 sc1"
                     : "=v"(fv) : "v"(fline) : "memory");
        asm volatile("s_waitcnt vmcnt(0)" ::: "memory");
        __builtin_amdgcn_sched_barrier(0);  // check must not hoist above wait
        int ok = (fv.x >= tgt) & (fv.y >= tgt) & (fv.z >= tgt) & (fv.w >= tgt);
        if (__all(ok)) break;
        __builtin_amdgcn_s_sleep(1);
      }
      asm volatile("" ::: "memory");  // no next-step load hoist above the poll
    }
  }
  // final OUT stores for t = NS-1
#pragma unroll
  for (int j = 0; j < 4; ++j)
    __builtin_nontemporal_store(
        v[j], &OUT[((size_t)(rowbase + crow + j) * NS + (NS - 1)) * DH + nbase + l15]);
}

// ---------------------------------------------------------------- launcher
extern "C" void kernel_launch(void* const* d_in, const int* in_sizes, int n_in,
                              void* d_out, int out_size, void* d_ws, size_t ws_size,
                              hipStream_t stream) {
  (void)in_sizes; (void)n_in; (void)out_size; (void)ws_size;
  const float* X   = (const float*)d_in[0];
  const float* Wxh = (const float*)d_in[1];
  const float* Whh = (const float*)d_in[2];
  const float* bh  = (const float*)d_in[3];
  float* out = (float*)d_out;

  char* ws = (char*)d_ws;
  // layout: wxh_t 2MB | whh_t 2MB | xp 64MB | h 256KB | flags 1KB
  unsigned short* wxh_t = (unsigned short*)(ws);
  unsigned short* whh_t = (unsigned short*)(ws + (size_t)2 * 1024 * 1024);
  unsigned short* xp    = (unsigned short*)(ws + (size_t)4 * 1024 * 1024);
  unsigned short* hbuf  = (unsigned short*)(ws + 71303168ull);
  unsigned int*   flg   = (unsigned int*)(ws + 71565312ull);

  (void)hipMemsetAsync(flg, 0, 4096, stream);  // flags start at 0 each call
  k_transpose_bf16<<<1024, 256, 0, stream>>>(Wxh, wxh_t);
  k_transpose_bf16<<<1024, 256, 0, stream>>>(Whh, whh_t);
  k_xproj<<<2048, 256, 0, stream>>>(X, wxh_t, xp);
  k_rnn<<<64, 256, 0, stream>>>(whh_t, xp, bh, out, hbuf, flg);
}

// Round 7
// 1875.416 us; speedup vs baseline: 2.0353x; 2.0353x over previous
//
#include <hip/hip_runtime.h>
#include <cstdint>

// MyRNN: out[b,t,:] = h_t where h_t = tanh(x[b,t,:]@W_xh + b_h + h_{t-1}@W_hh)
// B=64, S=512, D_IN=D_H=1024, fp32 I/O; internal bf16 MFMA.
//
// Round 7 = Round-5 structure (coalesced staging -> LDS -> MFMA) plus:
//  - padded LDS rows (129 x 16B slots): bank-optimal on write AND read, no XOR
//  - plain flag-store arrivals (no atomic RMW): flags[bg][ng][w] = t+1,
//    poll via one dwordx4/lane + __all
//  - OUT stores + xp prefetch issued under the poll (not in staging window)

#define DIN 1024
#define DH  1024
#define NB  64
#define NS  512

typedef __attribute__((ext_vector_type(8))) unsigned short us8;
typedef __attribute__((ext_vector_type(8))) __bf16 bf8;
typedef __attribute__((ext_vector_type(4))) float f32x4;
typedef __attribute__((ext_vector_type(4))) unsigned int u32x4;

__device__ __forceinline__ unsigned short f32_bf16(float f) {
  unsigned u = __float_as_uint(f);
  u = (u + 0x7fffu + ((u >> 16) & 1u)) >> 16;
  return (unsigned short)u;
}
__device__ __forceinline__ float bf16_f32(unsigned short h) {
  return __uint_as_float(((unsigned)h) << 16);
}
__device__ __forceinline__ bf8 as_bf8(us8 v) { return __builtin_bit_cast(bf8, v); }

// 16B load with coherent-point bypass (sc0 sc1). Caller must s_waitcnt.
__device__ __forceinline__ us8 load_sc16(const us8* p) {
  us8 r;
  asm volatile("global_load_dwordx4 %0, %1, off sc0 sc1"
               : "=v"(r) : "v"(p) : "memory");
  return r;
}

// ---------------------------------------------------------------- transpose
__global__ __launch_bounds__(256) void k_transpose_bf16(
    const float* __restrict__ W, unsigned short* __restrict__ WT) {
  __shared__ float tile[32][33];
  const int b  = blockIdx.x;
  const int bn = (b & 31) * 32;
  const int bk = (b >> 5) * 32;
  const int tx = threadIdx.x & 31, ty = threadIdx.x >> 5;
#pragma unroll
  for (int i = 0; i < 4; ++i)
    tile[ty + i * 8][tx] = W[(size_t)(bk + ty + i * 8) * DH + bn + tx];
  __syncthreads();
#pragma unroll
  for (int i = 0; i < 4; ++i)
    WT[(size_t)(bn + ty + i * 8) * DIN + bk + tx] = f32_bf16(tile[tx][ty + i * 8]);
}

// ---------------------------------------------------------------- phase 1
__device__ __forceinline__ int lds_idx(int row, int slot) {  // ushort units
  return row * 32 + ((slot ^ ((row >> 1) & 3)) << 3);
}

__global__ __launch_bounds__(256) void k_xproj(
    const float* __restrict__ X,             // [B*S][DIN] fp32
    const unsigned short* __restrict__ WT,   // W_xh^T bf16 [n][k]
    unsigned short* __restrict__ XP) {       // bf16 [s][b][h]
  __shared__ unsigned short As[128 * 32];
  __shared__ unsigned short Bs[128 * 32];
  const int tid = threadIdx.x;
  const int m0 = (int)(blockIdx.x >> 3) * 128;
  const int n0 = (int)(blockIdx.x & 7) * 128;
  const int w = tid >> 6, lane = tid & 63;
  const int wm = (w >> 1) * 64, wn = (w & 1) * 64;
  const int l15 = lane & 15, lhi = lane >> 4;
  const int srow = tid >> 1;
  const int s0 = (tid & 1) * 2;
  f32x4 acc[4][4] = {};

  for (int k0 = 0; k0 < DIN; k0 += 32) {
    const float4* ga = reinterpret_cast<const float4*>(
        X + (size_t)(m0 + srow) * DIN + k0 + s0 * 8);
    float4 f0 = ga[0], f1 = ga[1], f2 = ga[2], f3 = ga[3];
    us8 v0, v1;
    v0[0] = f32_bf16(f0.x); v0[1] = f32_bf16(f0.y); v0[2] = f32_bf16(f0.z); v0[3] = f32_bf16(f0.w);
    v0[4] = f32_bf16(f1.x); v0[5] = f32_bf16(f1.y); v0[6] = f32_bf16(f1.z); v0[7] = f32_bf16(f1.w);
    v1[0] = f32_bf16(f2.x); v1[1] = f32_bf16(f2.y); v1[2] = f32_bf16(f2.z); v1[3] = f32_bf16(f2.w);
    v1[4] = f32_bf16(f3.x); v1[5] = f32_bf16(f3.y); v1[6] = f32_bf16(f3.z); v1[7] = f32_bf16(f3.w);
    *(us8*)&As[lds_idx(srow, s0)]     = v0;
    *(us8*)&As[lds_idx(srow, s0 + 1)] = v1;
    const unsigned short* gb = WT + (size_t)(n0 + srow) * DIN + k0 + s0 * 8;
    *(us8*)&Bs[lds_idx(srow, s0)]     = *reinterpret_cast<const us8*>(gb);
    *(us8*)&Bs[lds_idx(srow, s0 + 1)] = *reinterpret_cast<const us8*>(gb + 8);
    __syncthreads();

    bf8 af[4], bfr[4];
#pragma unroll
    for (int i = 0; i < 4; ++i)
      af[i] = as_bf8(*(const us8*)&As[lds_idx(wm + i * 16 + l15, lhi)]);
#pragma unroll
    for (int r = 0; r < 4; ++r)
      bfr[r] = as_bf8(*(const us8*)&Bs[lds_idx(wn + r * 16 + l15, lhi)]);
#pragma unroll
    for (int i = 0; i < 4; ++i)
#pragma unroll
      for (int r = 0; r < 4; ++r)
        acc[i][r] = __builtin_amdgcn_mfma_f32_16x16x32_bf16(af[i], bfr[r], acc[i][r], 0, 0, 0);
    __syncthreads();
  }
#pragma unroll
  for (int i = 0; i < 4; ++i)
#pragma unroll
    for (int r = 0; r < 4; ++r)
#pragma unroll
      for (int j = 0; j < 4; ++j) {
        int gm = m0 + wm + i * 16 + lhi * 4 + j;
        int gn = n0 + wn + r * 16 + l15;
        int orow = ((gm & 511) << 6) | (gm >> 9);
        XP[(size_t)orow * DH + gn] = f32_bf16(acc[i][r][j]);
      }
}

// ---------------------------------------------------------------- phase 2
// 64 WGs x 256 thr. WG g: bg=g>>4 (rows bg*16..+16), ng=g&15; wave w owns
// cols ng*64+w*16..+16. W_hh^T slice resident in 128 VGPRs/wave.
// LDS h tile: 2 buffers x [16 rows][129 slots] (16B slots, +1 pad slot/row):
// bank-optimal on both tid-linear writes and (l15, kk*4+lhi) reads.
__global__ __launch_bounds__(256) void k_rnn(
    const unsigned short* __restrict__ WT,  // W_hh^T bf16 [n][k]
    const unsigned short* __restrict__ XP,  // bf16 [s][b][h]
    const float* __restrict__ BH,           // b_h fp32
    float* __restrict__ OUT,                // fp32 [b][s][h]
    unsigned short* __restrict__ H,         // 2 x [NB][DH] bf16
    unsigned int* __restrict__ flags) {     // [4 bg][16 ng][4 w] u32
  __shared__ us8 hs[2][16 * 129];           // 2 x 33,024B
  const int tid = threadIdx.x, g = blockIdx.x;
  const int w = tid >> 6, lane = tid & 63;
  const int bg = g >> 4, ng = g & 15;
  const int nbase = ng * 64 + w * 16;
  const int rowbase = bg * 16;
  const int l15 = lane & 15, lhi = lane >> 4;
  const int crow = lhi * 4;
  const int th = tid >> 7;                  // staging row parity
  const int c7 = tid & 127;                 // staging chunk-in-row
  const int rbase = l15 * 129;              // read: row base (16B slots)

  // preload W_hh^T fragments: 32 x 16B per lane = 128 VGPRs
  bf8 bw[32];
  const unsigned short* wp = WT + (size_t)(nbase + l15) * DIN + lhi * 8;
#pragma unroll
  for (int kk = 0; kk < 32; ++kk)
    bw[kk] = as_bf8(*reinterpret_cast<const us8*>(wp + kk * 32));

  const float bh = BH[nbase + l15];
  unsigned int* myflag = flags + bg * 64 + ng * 4 + w;
  // poll source: lane reads 16B chunk (lane&15) of the bg's 256B flag block
  const u32x4* fline = reinterpret_cast<const u32x4*>(flags + bg * 64) + l15;

  // prefetch xp for t=0
  float xq[4];
#pragma unroll
  for (int j = 0; j < 4; ++j)
    xq[j] = bf16_f32(XP[(size_t)(rowbase + crow + j) * DH + nbase + l15]);

  float v[4] = {0.f, 0.f, 0.f, 0.f};

#pragma unroll 1
  for (int t = 0; t < NS; ++t) {
    const int pb = t & 1;
    f32x4 a0 = {}, a1 = {}, a2 = {}, a3 = {};
    if (t > 0) {
      // ---- stage h[pb] -> hs[pb]: coalesced tid-linear 16B sc-bypass loads
      const us8* hg = reinterpret_cast<const us8*>(H) +
                      (size_t)pb * 8192 + rowbase * 128 + tid;
      us8 hv[8];
#pragma unroll
      for (int i = 0; i < 8; ++i) hv[i] = load_sc16(hg + 256 * i);
      asm volatile("s_waitcnt vmcnt(0)" ::: "memory");
      __builtin_amdgcn_sched_barrier(0);
#pragma unroll
      for (int i = 0; i < 8; ++i) {
        const int r = 2 * i + th;
        hs[pb][r * 129 + c7] = hv[i];
      }
      __syncthreads();  // the ONLY barrier per step
      // ---- A-fragment reads + 32 MFMA (bank-optimal padded reads) ----
#pragma unroll
      for (int kk = 0; kk < 32; kk += 4) {
        bf8 h0 = as_bf8(hs[pb][rbase + (kk + 0) * 4 + lhi]);
        bf8 h1 = as_bf8(hs[pb][rbase + (kk + 1) * 4 + lhi]);
        bf8 h2 = as_bf8(hs[pb][rbase + (kk + 2) * 4 + lhi]);
        bf8 h3 = as_bf8(hs[pb][rbase + (kk + 3) * 4 + lhi]);
        a0 = __builtin_amdgcn_mfma_f32_16x16x32_bf16(h0, bw[kk],     a0, 0, 0, 0);
        a1 = __builtin_amdgcn_mfma_f32_16x16x32_bf16(h1, bw[kk + 1], a1, 0, 0, 0);
        a2 = __builtin_amdgcn_mfma_f32_16x16x32_bf16(h2, bw[kk + 2], a2, 0, 0, 0);
        a3 = __builtin_amdgcn_mfma_f32_16x16x32_bf16(h3, bw[kk + 3], a3, 0, 0, 0);
      }
    }
    f32x4 s = (a0 + a1) + (a2 + a3);

#pragma unroll
    for (int j = 0; j < 4; ++j) {
      float x = xq[j] + s[j] + bh;
      float e = __expf(-2.f * fabsf(x));
      float r = __fdividef(1.f - e, 1.f + e);
      v[j] = copysignf(r, x);
    }

    if (t < NS - 1) {
      // h stores to coherent point, drain, then plain flag store (no RMW)
      unsigned short* hnext = H + (size_t)(pb ^ 1) * (NB * DH);
#pragma unroll
      for (int j = 0; j < 4; ++j)
        __hip_atomic_store(hnext + (size_t)(rowbase + crow + j) * DH + nbase + l15,
                           f32_bf16(v[j]), __ATOMIC_RELAXED, __HIP_MEMORY_SCOPE_AGENT);
      asm volatile("s_waitcnt vmcnt(0)" ::: "memory");  // drain THIS wave's h
      if (lane == 0)
        __hip_atomic_store(myflag, (unsigned)(t + 1), __ATOMIC_RELAXED,
                           __HIP_MEMORY_SCOPE_AGENT);
      // off-critical-path work rides under the poll:
#pragma unroll
      for (int j = 0; j < 4; ++j)
        __builtin_nontemporal_store(
            v[j], &OUT[((size_t)(rowbase + crow + j) * NS + t) * DH + nbase + l15]);
#pragma unroll
      for (int j = 0; j < 4; ++j)
        xq[j] = bf16_f32(XP[(size_t)(((t + 1) << 6) + rowbase + crow + j) * DH +
                            nbase + l15]);
      const unsigned tgt = (unsigned)(t + 1);
      for (;;) {
        u32x4 fv;
        asm volatile("global_load_dwordx4 %0, %1, off sc0 sc1"
                     : "=v"(fv) : "v"(fline) : "memory");
        asm volatile("s_waitcnt vmcnt(0)" ::: "memory");
        __builtin_amdgcn_sched_barrier(0);
        int ok = (fv.x >= tgt) & (fv.y >= tgt) & (fv.z >= tgt) & (fv.w >= tgt);
        if (__all(ok)) break;
        __builtin_amdgcn_s_sleep(1);
      }
      asm volatile("" ::: "memory");  // no next-step load hoist above the poll
    }
  }
  // final OUT stores for t = NS-1
#pragma unroll
  for (int j = 0; j < 4; ++j)
    __builtin_nontemporal_store(
        v[j], &OUT[((size_t)(rowbase + crow + j) * NS + (NS - 1)) * DH + nbase + l15]);
}

// ---------------------------------------------------------------- launcher
extern "C" void kernel_launch(void* const* d_in, const int* in_sizes, int n_in,
                              void* d_out, int out_size, void* d_ws, size_t ws_size,
                              hipStream_t stream) {
  (void)in_sizes; (void)n_in; (void)out_size; (void)ws_size;
  const float* X   = (const float*)d_in[0];
  const float* Wxh = (const float*)d_in[1];
  const float* Whh = (const float*)d_in[2];
  const float* bh  = (const float*)d_in[3];
  float* out = (float*)d_out;

  char* ws = (char*)d_ws;
  // layout: wxh_t 2MB | whh_t 2MB | xp 64MB | h 256KB | flags 4KB
  unsigned short* wxh_t = (unsigned short*)(ws);
  unsigned short* whh_t = (unsigned short*)(ws + (size_t)2 * 1024 * 1024);
  unsigned short* xp    = (unsigned short*)(ws + (size_t)4 * 1024 * 1024);
  unsigned short* hbuf  = (unsigned short*)(ws + 71303168ull);
  unsigned int*   flg   = (unsigned int*)(ws + 71565312ull);

  (void)hipMemsetAsync(flg, 0, 4096, stream);  // flags start at 0 each call
  k_transpose_bf16<<<1024, 256, 0, stream>>>(Wxh, wxh_t);
  k_transpose_bf16<<<1024, 256, 0, stream>>>(Whh, whh_t);
  k_xproj<<<2048, 256, 0, stream>>>(X, wxh_t, xp);
  k_rnn<<<64, 256, 0, stream>>>(whh_t, xp, bh, out, hbuf, flg);
}

// Round 8
// 1827.460 us; speedup vs baseline: 2.0887x; 1.0262x over previous
//
#include <hip/hip_runtime.h>
#include <cstdint>

// MyRNN: out[b,t,:] = h_t where h_t = tanh(x[b,t,:]@W_xh + b_h + h_{t-1}@W_hh)
// B=64, S=512, D_IN=D_H=1024, fp32 I/O; internal bf16 MFMA.
//
// Round 8: tag-embedded h exchange. h stored as u32 {bf16<<16 | (t+1)};
// consumers spin on the DATA (reload + check 64 tags), no producer drain,
// no flags, no separate poll -> one MALL RT instead of three.
// H32 is memset to 0 each call (kills replay staleness of tags).
// OUT stores ride inside the staging window (acks hidden under load RT).

#define DIN 1024
#define DH  1024
#define NB  64
#define NS  512

typedef __attribute__((ext_vector_type(8))) unsigned short us8;
typedef __attribute__((ext_vector_type(8))) __bf16 bf8;
typedef __attribute__((ext_vector_type(4))) float f32x4;
typedef __attribute__((ext_vector_type(4))) unsigned int u32x4;

__device__ __forceinline__ unsigned short f32_bf16(float f) {
  unsigned u = __float_as_uint(f);
  u = (u + 0x7fffu + ((u >> 16) & 1u)) >> 16;
  return (unsigned short)u;
}
__device__ __forceinline__ float bf16_f32(unsigned short h) {
  return __uint_as_float(((unsigned)h) << 16);
}
__device__ __forceinline__ bf8 as_bf8(us8 v) { return __builtin_bit_cast(bf8, v); }

// 16B load with coherent-point bypass (sc0 sc1). Caller must s_waitcnt.
__device__ __forceinline__ u32x4 load_sc16u(const u32x4* p) {
  u32x4 r;
  asm volatile("global_load_dwordx4 %0, %1, off sc0 sc1"
               : "=v"(r) : "v"(p) : "memory");
  return r;
}

// ---------------------------------------------------------------- transpose
__global__ __launch_bounds__(256) void k_transpose_bf16(
    const float* __restrict__ W, unsigned short* __restrict__ WT) {
  __shared__ float tile[32][33];
  const int b  = blockIdx.x;
  const int bn = (b & 31) * 32;
  const int bk = (b >> 5) * 32;
  const int tx = threadIdx.x & 31, ty = threadIdx.x >> 5;
#pragma unroll
  for (int i = 0; i < 4; ++i)
    tile[ty + i * 8][tx] = W[(size_t)(bk + ty + i * 8) * DH + bn + tx];
  __syncthreads();
#pragma unroll
  for (int i = 0; i < 4; ++i)
    WT[(size_t)(bn + ty + i * 8) * DIN + bk + tx] = f32_bf16(tile[tx][ty + i * 8]);
}

// ---------------------------------------------------------------- phase 1
__device__ __forceinline__ int lds_idx(int row, int slot) {  // ushort units
  return row * 32 + ((slot ^ ((row >> 1) & 3)) << 3);
}

__global__ __launch_bounds__(256) void k_xproj(
    const float* __restrict__ X,             // [B*S][DIN] fp32
    const unsigned short* __restrict__ WT,   // W_xh^T bf16 [n][k]
    unsigned short* __restrict__ XP) {       // bf16 [s][b][h]
  __shared__ unsigned short As[128 * 32];
  __shared__ unsigned short Bs[128 * 32];
  const int tid = threadIdx.x;
  const int m0 = (int)(blockIdx.x >> 3) * 128;
  const int n0 = (int)(blockIdx.x & 7) * 128;
  const int w = tid >> 6, lane = tid & 63;
  const int wm = (w >> 1) * 64, wn = (w & 1) * 64;
  const int l15 = lane & 15, lhi = lane >> 4;
  const int srow = tid >> 1;
  const int s0 = (tid & 1) * 2;
  f32x4 acc[4][4] = {};

  for (int k0 = 0; k0 < DIN; k0 += 32) {
    const float4* ga = reinterpret_cast<const float4*>(
        X + (size_t)(m0 + srow) * DIN + k0 + s0 * 8);
    float4 f0 = ga[0], f1 = ga[1], f2 = ga[2], f3 = ga[3];
    us8 v0, v1;
    v0[0] = f32_bf16(f0.x); v0[1] = f32_bf16(f0.y); v0[2] = f32_bf16(f0.z); v0[3] = f32_bf16(f0.w);
    v0[4] = f32_bf16(f1.x); v0[5] = f32_bf16(f1.y); v0[6] = f32_bf16(f1.z); v0[7] = f32_bf16(f1.w);
    v1[0] = f32_bf16(f2.x); v1[1] = f32_bf16(f2.y); v1[2] = f32_bf16(f2.z); v1[3] = f32_bf16(f2.w);
    v1[4] = f32_bf16(f3.x); v1[5] = f32_bf16(f3.y); v1[6] = f32_bf16(f3.z); v1[7] = f32_bf16(f3.w);
    *(us8*)&As[lds_idx(srow, s0)]     = v0;
    *(us8*)&As[lds_idx(srow, s0 + 1)] = v1;
    const unsigned short* gb = WT + (size_t)(n0 + srow) * DIN + k0 + s0 * 8;
    *(us8*)&Bs[lds_idx(srow, s0)]     = *reinterpret_cast<const us8*>(gb);
    *(us8*)&Bs[lds_idx(srow, s0 + 1)] = *reinterpret_cast<const us8*>(gb + 8);
    __syncthreads();

    bf8 af[4], bfr[4];
#pragma unroll
    for (int i = 0; i < 4; ++i)
      af[i] = as_bf8(*(const us8*)&As[lds_idx(wm + i * 16 + l15, lhi)]);
#pragma unroll
    for (int r = 0; r < 4; ++r)
      bfr[r] = as_bf8(*(const us8*)&Bs[lds_idx(wn + r * 16 + l15, lhi)]);
#pragma unroll
    for (int i = 0; i < 4; ++i)
#pragma unroll
      for (int r = 0; r < 4; ++r)
        acc[i][r] = __builtin_amdgcn_mfma_f32_16x16x32_bf16(af[i], bfr[r], acc[i][r], 0, 0, 0);
    __syncthreads();
  }
#pragma unroll
  for (int i = 0; i < 4; ++i)
#pragma unroll
    for (int r = 0; r < 4; ++r)
#pragma unroll
      for (int j = 0; j < 4; ++j) {
        int gm = m0 + wm + i * 16 + lhi * 4 + j;
        int gn = n0 + wn + r * 16 + l15;
        int orow = ((gm & 511) << 6) | (gm >> 9);
        XP[(size_t)orow * DH + gn] = f32_bf16(acc[i][r][j]);
      }
}

// ---------------------------------------------------------------- phase 2
// 64 WGs x 256 thr. WG g: bg=g>>4 (rows bg*16..+16), ng=g&15; wave w owns
// cols ng*64+w*16..+16. W_hh^T slice resident in 128 VGPRs/wave.
// h exchange: H32 = 2 x [64][1024] u32, each {bf16 value <<16 | (step+1)}.
// Consumer stages its 16x1024 u32 tile (16 dwordx4/thread, coalesced),
// spins until all 64 tags == t, strips tags, writes padded LDS, 32 MFMA.
__global__ __launch_bounds__(256) void k_rnn(
    const unsigned short* __restrict__ WT,  // W_hh^T bf16 [n][k]
    const unsigned short* __restrict__ XP,  // bf16 [s][b][h]
    const float* __restrict__ BH,           // b_h fp32
    float* __restrict__ OUT,                // fp32 [b][s][h]
    unsigned int* __restrict__ H32) {       // 2 x [NB][DH] u32 (memset 0)
  __shared__ us8 hs[2][16 * 129];           // 2 x 33,024B, padded rows
  const int tid = threadIdx.x, g = blockIdx.x;
  const int w = tid >> 6, lane = tid & 63;
  const int bg = g >> 4, ng = g & 15;
  const int nbase = ng * 64 + w * 16;
  const int rowbase = bg * 16;
  const int l15 = lane & 15, lhi = lane >> 4;
  const int crow = lhi * 4;
  const int rbase = l15 * 129;              // read: row base (16B slots)
  const int wslot = tid >> 1;               // write: slot within row
  const int whalf = (tid & 1) * 8;          // write: byte half within slot

  // preload W_hh^T fragments: 32 x 16B per lane = 128 VGPRs
  bf8 bw[32];
  const unsigned short* wp = WT + (size_t)(nbase + l15) * DIN + lhi * 8;
#pragma unroll
  for (int kk = 0; kk < 32; ++kk)
    bw[kk] = as_bf8(*reinterpret_cast<const us8*>(wp + kk * 32));

  const float bh = BH[nbase + l15];

  // prefetch xp for t=0
  float xq[4];
#pragma unroll
  for (int j = 0; j < 4; ++j)
    xq[j] = bf16_f32(XP[(size_t)(rowbase + crow + j) * DH + nbase + l15]);

  float v[4] = {0.f, 0.f, 0.f, 0.f};

#pragma unroll 1
  for (int t = 0; t < NS; ++t) {
    const int pb = t & 1;
    f32x4 a0 = {}, a1 = {}, a2 = {}, a3 = {};
    if (t > 0) {
      // ---- staged spin on tagged data: thread covers rows 0..15 at u32
      // cols tid*4..+3 (chunk stride = one row = 256 chunks) ----
      const u32x4* hg = reinterpret_cast<const u32x4*>(
                            H32 + (size_t)pb * (NB * DH) + rowbase * DH) + tid;
      u32x4 hv[16];
#pragma unroll
      for (int i = 0; i < 16; ++i) hv[i] = load_sc16u(hg + 256 * i);
      // OUT stores for t-1 ride inside the staging window
#pragma unroll
      for (int j = 0; j < 4; ++j)
        __builtin_nontemporal_store(
            v[j],
            &OUT[((size_t)(rowbase + crow + j) * NS + (t - 1)) * DH + nbase + l15]);
      const unsigned tagv = (unsigned)t;
      for (;;) {
        asm volatile("s_waitcnt vmcnt(0)" ::: "memory");
        __builtin_amdgcn_sched_barrier(0);
        unsigned diff = 0;
#pragma unroll
        for (int i = 0; i < 16; ++i) {
          diff |= (hv[i].x ^ tagv);
          diff |= (hv[i].y ^ tagv);
          diff |= (hv[i].z ^ tagv);
          diff |= (hv[i].w ^ tagv);
        }
        if (__all((diff & 0xffffu) == 0u)) break;
        __builtin_amdgcn_s_sleep(1);
#pragma unroll
        for (int i = 0; i < 16; ++i) hv[i] = load_sc16u(hg + 256 * i);
      }
      // ---- strip tags, pack to bf16, write padded LDS ----
#pragma unroll
      for (int i = 0; i < 16; ++i) {
        unsigned p0 = (hv[i].x >> 16) | (hv[i].y & 0xffff0000u);
        unsigned p1 = (hv[i].z >> 16) | (hv[i].w & 0xffff0000u);
        unsigned long long pk = ((unsigned long long)p1 << 32) | p0;
        *reinterpret_cast<unsigned long long*>(
            reinterpret_cast<char*>(&hs[pb][i * 129 + wslot]) + whalf) = pk;
      }
      __syncthreads();  // the ONLY barrier per step
      // ---- A-fragment reads + 32 MFMA (bank-uniform padded reads) ----
#pragma unroll
      for (int kk = 0; kk < 32; kk += 4) {
        bf8 h0 = as_bf8(hs[pb][rbase + (kk + 0) * 4 + lhi]);
        bf8 h1 = as_bf8(hs[pb][rbase + (kk + 1) * 4 + lhi]);
        bf8 h2 = as_bf8(hs[pb][rbase + (kk + 2) * 4 + lhi]);
        bf8 h3 = as_bf8(hs[pb][rbase + (kk + 3) * 4 + lhi]);
        a0 = __builtin_amdgcn_mfma_f32_16x16x32_bf16(h0, bw[kk],     a0, 0, 0, 0);
        a1 = __builtin_amdgcn_mfma_f32_16x16x32_bf16(h1, bw[kk + 1], a1, 0, 0, 0);
        a2 = __builtin_amdgcn_mfma_f32_16x16x32_bf16(h2, bw[kk + 2], a2, 0, 0, 0);
        a3 = __builtin_amdgcn_mfma_f32_16x16x32_bf16(h3, bw[kk + 3], a3, 0, 0, 0);
      }
    }
    f32x4 s = (a0 + a1) + (a2 + a3);

#pragma unroll
    for (int j = 0; j < 4; ++j) {
      float x = xq[j] + s[j] + bh;
      float e = __expf(-2.f * fabsf(x));
      float r = __fdividef(1.f - e, 1.f + e);
      v[j] = copysignf(r, x);
    }

    if (t < NS - 1) {
      // tagged h stores (fire-and-forget: no drain, no flag)
      unsigned int* hn = H32 + (size_t)(pb ^ 1) * (NB * DH);
      const unsigned tagn = (unsigned)(t + 1);
#pragma unroll
      for (int j = 0; j < 4; ++j) {
        unsigned pv = (((unsigned)f32_bf16(v[j])) << 16) | tagn;
        __hip_atomic_store(hn + (size_t)(rowbase + crow + j) * DH + nbase + l15,
                           pv, __ATOMIC_RELAXED, __HIP_MEMORY_SCOPE_AGENT);
      }
      // xp prefetch for t+1 (drained by next staging's vmcnt)
#pragma unroll
      for (int j = 0; j < 4; ++j)
        xq[j] = bf16_f32(XP[(size_t)(((t + 1) << 6) + rowbase + crow + j) * DH +
                            nbase + l15]);
    }
  }
  // final OUT stores for t = NS-1
#pragma unroll
  for (int j = 0; j < 4; ++j)
    __builtin_nontemporal_store(
        v[j], &OUT[((size_t)(rowbase + crow + j) * NS + (NS - 1)) * DH + nbase + l15]);
}

// ---------------------------------------------------------------- launcher
extern "C" void kernel_launch(void* const* d_in, const int* in_sizes, int n_in,
                              void* d_out, int out_size, void* d_ws, size_t ws_size,
                              hipStream_t stream) {
  (void)in_sizes; (void)n_in; (void)out_size; (void)ws_size;
  const float* X   = (const float*)d_in[0];
  const float* Wxh = (const float*)d_in[1];
  const float* Whh = (const float*)d_in[2];
  const float* bh  = (const float*)d_in[3];
  float* out = (float*)d_out;

  char* ws = (char*)d_ws;
  // layout: wxh_t 2MB | whh_t 2MB | H32 512KB | xp 64MB   (total 68.5MB)
  unsigned short* wxh_t = (unsigned short*)(ws);
  unsigned short* whh_t = (unsigned short*)(ws + (size_t)2 * 1024 * 1024);
  unsigned int*   h32   = (unsigned int*)(ws + (size_t)4 * 1024 * 1024);
  unsigned short* xp    = (unsigned short*)(ws + 4718592ull);

  // tags must be invalid (0) at every call start (graph replays included)
  (void)hipMemsetAsync(h32, 0, 524288, stream);
  k_transpose_bf16<<<1024, 256, 0, stream>>>(Wxh, wxh_t);
  k_transpose_bf16<<<1024, 256, 0, stream>>>(Whh, whh_t);
  k_xproj<<<2048, 256, 0, stream>>>(X, wxh_t, xp);
  k_rnn<<<64, 256, 0, stream>>>(whh_t, xp, bh, out, h32);
}